// Round 12
// baseline (4403.330 us; speedup 1.0000x reference)
//
#include <hip/hip_runtime.h>
#include <hip/hip_bf16.h>
#include <hip/hip_fp16.h>

// GRU forward, MI355X. Harness gives f32 buffers (reference f16 -> f32).
// x:(512,64,1024) h0:(1,64,1024) w_ih,w_hh:(3072,1024) b:(3072) y:(512,64,1024).
//
// PROTOCOL (r2/4/8/9/11, five-times-proven, absmax 0.0078125):
// per-step: gate math -> h (packed u32 RELAXED agent write-through);
// s_waitcnt vmcnt(0); __syncthreads; tid0 stores flag (RELAXED agent,
// PRIVATE 128B line); gi prefetch; wave0 gather-polls 64 flags w/ s_sleep;
// __syncthreads. r9 load-pin kept.
//
// FROZEN BY EXPERIMENT:
//  - Y AFTER the flag store    -> absmax 0.117 (r3, r6)
//  - nontemporal loads/stores  -> absmax 0.117 (r3)
//  - per-band fetch_add sync   -> absmax 0.048 + 7395us (r5)
//  - flags packed 4B stride    -> absmax 0.083 (r7)
//  - gi_gemm BK=64 reg-staged  -> +200us (r10)
//
// Round 19 (this round), two independently-attributable changes:
//  1. SCAN: Y store lag-by-one -- Y[t-1] stored from hreg at the TOP of
//     step t (before MFMA), not inside the gate loop. Y stays BEFORE the
//     flag store in program order (the failed variant was Y AFTER flag);
//     the per-step vmcnt(0) drain now waits only the 4 h write-throughs,
//     not 16 fresh Y acks (Y gets ~2us of MFMA+gates to retire).
//     Epilogue stores Y[511]. Values bit-identical.
//  2. GEMM: minimum-2-phase staging (catalog T3-lite): double-buffered
//     LDS; issue next K-tile's global_load_lds BEFORE current ds_read+MFMA;
//     one vmcnt(0)+barrier per iter. Fragment map & ascending-K MFMA order
//     unchanged -> gi BIT-IDENTICAL.
// Attribution: scan-dur counter isolates (1); total-scan isolates (2);
// absmax ~0.08-0.12 would implicate (1) -> revert.

typedef __attribute__((ext_vector_type(8))) _Float16 f16x8;
typedef __attribute__((ext_vector_type(4))) float f32x4;
typedef __attribute__((ext_vector_type(8))) float f32x8;

#define MFMA(a, b, c) __builtin_amdgcn_mfma_f32_16x16x32_f16((a), (b), (c), 0, 0, 0)

#define T_T 512
#define T_B 64
#define T_K 1024
#define T_N3 3072

__device__ float          g_gi[(size_t)T_T * T_B * T_N3];   // 402 MiB f32 gi
__device__ unsigned short g_hbf[(size_t)T_T * T_B * T_K];   // 64 MiB f16 h_t
__device__ unsigned       g_flags[64 * 32];                 // 128B-padded flags
__device__ unsigned short g_xh[(size_t)T_T * T_B * T_K];    // 64 MiB f16 X
__device__ unsigned short g_wh[(size_t)T_N3 * T_K];         // 6 MiB f16 Wih

static __device__ __forceinline__ f16x8 cvt8(f32x8 v) {
    f16x8 r;
    #pragma unroll
    for (int i = 0; i < 8; ++i) r[i] = (_Float16)v[i];
    return r;
}
static __device__ __forceinline__ float sigmoidf_(float x) {
    return 1.0f / (1.0f + __expf(-x));
}
static __device__ __forceinline__ float tanhf_(float x) {
    return 2.0f / (1.0f + __expf(-2.0f * x)) - 1.0f;
}

__global__ __launch_bounds__(256) void reset_flags_k() {
    for (int i = threadIdx.x; i < 64 * 32; i += 256) g_flags[i] = 0;
}

// ---------------------------------------------------------------------------
// Kernel 0: convert X and Wih to f16 (same RNE rounding as inline cvt8).
// ---------------------------------------------------------------------------
__global__ __launch_bounds__(256) void cvt_k(
    const float* __restrict__ X,     // (32768,1024) f32
    const float* __restrict__ W)     // (3072,1024) f32
{
    const size_t NX = (size_t)T_T * T_B * T_K / 8;
    const size_t NW = (size_t)T_N3 * T_K / 8;
    size_t i0 = (size_t)blockIdx.x * 256 + threadIdx.x;
    size_t stride = (size_t)gridDim.x * 256;
    for (size_t i = i0; i < NX; i += stride)
        ((f16x8*)g_xh)[i] = cvt8(((const f32x8*)X)[i]);
    for (size_t i = i0; i < NW; i += stride)
        ((f16x8*)g_wh)[i] = cvt8(((const f32x8*)W)[i]);
}

// ---------------------------------------------------------------------------
// Kernel 1: gi = X @ Wih^T + bih, f32 out. f16 MFMA, BK=32, 2-phase
// double-buffered global_load_lds staging, XCD-swizzled blockIdx.
// Same fragment map / K order as r11 -> gi bit-identical.
// ---------------------------------------------------------------------------
__global__ __launch_bounds__(256) void gi_gemm(
    const float* __restrict__ bih)   // (3072,) f32
{
    __shared__ __align__(16) unsigned short lA[2][128 * 32];  // 16 KiB
    __shared__ __align__(16) unsigned short lB[2][128 * 32];  // 16 KiB
    const int tid  = threadIdx.x;
    const int lane = tid & 63;
    const int wid  = tid >> 6;
    const int swz = (blockIdx.x & 7) * 768 + (blockIdx.x >> 3);
    const int m0 = (swz / 24) * 128;
    const int n0 = (swz % 24) * 128;
    const int wm = wid >> 1, wn = wid & 1;

    const int srow = tid >> 2;        // 0..63 (+64 on issue 1)
    const int skc  = tid & 3;

    auto stage = [&](int buf, int k0) {
        #pragma unroll
        for (int i = 0; i < 2; ++i) {
            const unsigned short* ga =
                g_xh + (size_t)(m0 + i * 64 + srow) * T_K + k0 + skc * 8;
            const unsigned short* gb =
                g_wh + (size_t)(n0 + i * 64 + srow) * T_K + k0 + skc * 8;
            char* la = (char*)lA + buf * 8192 + i * 4096 + wid * 1024;
            char* lb = (char*)lB + buf * 8192 + i * 4096 + wid * 1024;
            __builtin_amdgcn_global_load_lds(
                (const __attribute__((address_space(1))) unsigned int*)ga,
                (__attribute__((address_space(3))) unsigned int*)la, 16, 0, 0);
            __builtin_amdgcn_global_load_lds(
                (const __attribute__((address_space(1))) unsigned int*)gb,
                (__attribute__((address_space(3))) unsigned int*)lb, 16, 0, 0);
        }
    };

    f32x4 acc[4][4] = {};

    stage(0, 0);
    __syncthreads();                       // vmcnt(0) implied before barrier

    for (int it = 0; it < 32; ++it) {
        const int cur = it & 1;
        if (it < 31) stage(cur ^ 1, (it + 1) * 32);  // next tile in flight

        f16x8 a[4], b[4];
        #pragma unroll
        for (int mt = 0; mt < 4; ++mt) {
            int row = 64 * wm + 16 * mt + (lane & 15);
            a[mt] = *(const f16x8*)((const char*)lA + cur * 8192
                                    + row * 64 + (lane >> 4) * 16);
        }
        #pragma unroll
        for (int nt = 0; nt < 4; ++nt) {
            int row = 64 * wn + 16 * nt + (lane & 15);
            b[nt] = *(const f16x8*)((const char*)lB + cur * 8192
                                    + row * 64 + (lane >> 4) * 16);
        }
        #pragma unroll
        for (int mt = 0; mt < 4; ++mt)
            #pragma unroll
            for (int nt = 0; nt < 4; ++nt)
                acc[mt][nt] = MFMA(a[mt], b[nt], acc[mt][nt]);

        __syncthreads();   // drains this iter's stage; releases cur for reuse
    }

    #pragma unroll
    for (int mt = 0; mt < 4; ++mt) {
        int rbase = m0 + 64 * wm + 16 * mt + (lane >> 4) * 4;
        #pragma unroll
        for (int nt = 0; nt < 4; ++nt) {
            int col = n0 + 64 * wn + 16 * nt + (lane & 15);
            float bv = bih[col];
            #pragma unroll
            for (int j = 0; j < 4; ++j)
                g_gi[(size_t)(rbase + j) * T_N3 + col] = acc[mt][nt][j] + bv;
        }
    }
}

// ---------------------------------------------------------------------------
// Kernel 2: persistent GRU scan. 64 blocks x 256 threads, fence-free
// message passing. r9 protocol; Y store lag-by-one (still before flag).
// ---------------------------------------------------------------------------
__global__ __launch_bounds__(256, 1) void gru_scan(
    const float* __restrict__ Whh,   // (3072,1024) f32
    const float* __restrict__ Bhh,   // (3072,) f32
    const float* __restrict__ H0,    // (64,1024) f32
    float* Y)                        // (512,64,1024) f32
{
    __shared__ unsigned short Wl[48 * 1024];  // 96 KiB f16
    const int tid  = threadIdx.x;
    const int lane = tid & 63;
    const int w    = tid >> 6;
    const int c0   = blockIdx.x * 16;

    for (int idx = tid; idx < 48 * 128; idx += 256) {
        int row = idx >> 7;                   // gate*16 + c
        int kc  = idx & 127;
        int gate = row >> 4, cc = row & 15;
        f32x8 v = *(const f32x8*)(Whh + (size_t)(gate * 1024 + c0 + cc) * T_K + kc * 8);
        *(f16x8*)((char*)Wl + kc * 768 + row * 16) = cvt8(v);
    }
    const int colL = c0 + (lane & 15);
    const float br = Bhh[colL];
    const float bz = Bhh[1024 + colL];
    const float bn = Bhh[2048 + colL];
    __syncthreads();

    const char* bbase = (const char*)Wl + (lane >> 4) * 768 + (lane & 15) * 16;

    // Preload gi for t = 0 (f32, normal cached loads).
    float pr[4], pz[4], pn[4];
    #pragma unroll
    for (int j = 0; j < 4; ++j) {
        int row = 16 * w + (lane >> 4) * 4 + j;
        pr[j] = g_gi[(size_t)row * T_N3 + colL];
        pz[j] = g_gi[(size_t)row * T_N3 + 1024 + colL];
        pn[j] = g_gi[(size_t)row * T_N3 + 2048 + colL];
    }

    // Per-thread h chain registers (f16-rounded values, kept as f32).
    float hreg[4];

    for (int t = 0; t < T_T; ++t) {
        // Y lag-by-one: store Y[t-1] from hreg at step top -- issued early
        // so its acks retire under the MFMA+gate phase, off the drain path.
        // Program order: still BEFORE this step's flag store.
        if (t > 0) {
            #pragma unroll
            for (int j = 0; j < 4; ++j) {
                int row = 16 * w + (lane >> 4) * 4 + j;
                Y[(size_t)(t - 1) * (T_B * T_K) + (size_t)row * T_K + colL] = hreg[j];
            }
        }

        f32x4 ar = {0.f, 0.f, 0.f, 0.f}, az = ar, an = ar;

        if (t == 0) {
            const float* abase =
                H0 + (size_t)(16 * w + (lane & 15)) * T_K + (lane >> 4) * 8;
            #pragma unroll 4
            for (int kk = 0; kk < 32; ++kk) {
                f16x8 af = cvt8(*(const f32x8*)(abase + kk * 32));
                const char* bb = bbase + kk * 3072;
                ar = MFMA(af, *(const f16x8*)(bb),       ar);
                az = MFMA(af, *(const f16x8*)(bb + 256), az);
                an = MFMA(af, *(const f16x8*)(bb + 512), an);
            }
        } else {
            const unsigned short* abase = g_hbf + (size_t)(t - 1) * (T_B * T_K)
                + (size_t)(16 * w + (lane & 15)) * T_K + (lane >> 4) * 8;
            // Issue ALL 32 independent b128 loads, then a may-write asm
            // barrier: loads cannot sink past it -> one latency exposure.
            f16x8 af[32];
            #pragma unroll
            for (int kk = 0; kk < 32; ++kk)
                af[kk] = *(const f16x8*)(abase + kk * 32);
            asm volatile("" ::: "memory");
            #pragma unroll
            for (int kk = 0; kk < 32; ++kk) {
                const char* bb = bbase + kk * 3072;
                ar = MFMA(af[kk], *(const f16x8*)(bb),       ar);
                az = MFMA(af[kk], *(const f16x8*)(bb + 256), az);
                an = MFMA(af[kk], *(const f16x8*)(bb + 512), an);
            }
        }

        #pragma unroll
        for (int j = 0; j < 4; ++j) {
            int row = 16 * w + (lane >> 4) * 4 + j;
            size_t off = (size_t)row * T_K + colL;
            float hp = (t == 0) ? H0[off] : hreg[j];
            float r = sigmoidf_(pr[j] + ar[j] + br);
            float z = sigmoidf_(pz[j] + az[j] + bz);
            float n = tanhf_(pn[j] + r * (an[j] + bn));
            float h = (1.0f - z) * n + z * hp;
            __half h16 = __float2half(h);         // reference: astype(f16)
            float  hq  = __half2float(h16);
            hreg[j] = hq;

            // f16 h -> g_hbf via packed u32 relaxed agent store (write-through).
            unsigned v16 = (unsigned)__half_as_ushort(h16);
            unsigned up  = __shfl_xor(v16, 1);
            if (!(lane & 1)) {
                unsigned packed = v16 | (up << 16);
                unsigned* dst = (unsigned*)(g_hbf + (size_t)t * (T_B * T_K) + off);
                __hip_atomic_store(dst, packed, __ATOMIC_RELAXED,
                                   __HIP_MEMORY_SCOPE_AGENT);
            }
        }

        if (t + 1 < T_T) {
            // Drain vmem (h write-through; Y[t-1] long since issued), signal.
            asm volatile("s_waitcnt vmcnt(0)" ::: "memory");
            __syncthreads();
            if (tid == 0)
                __hip_atomic_store(&g_flags[blockIdx.x * 32], (unsigned)(t + 1),
                                   __ATOMIC_RELAXED, __HIP_MEMORY_SCOPE_AGENT);

            // Prefetch gi for t+1 while polling (normal cached loads).
            const float* g = g_gi + (size_t)(t + 1) * T_B * T_N3;
            #pragma unroll
            for (int j = 0; j < 4; ++j) {
                int row = 16 * w + (lane >> 4) * 4 + j;
                pr[j] = g[(size_t)row * T_N3 + colL];
                pz[j] = g[(size_t)row * T_N3 + 1024 + colL];
                pn[j] = g[(size_t)row * T_N3 + 2048 + colL];
            }

            if (w == 0) {
                unsigned tgt = (unsigned)(t + 1);
                for (;;) {
                    unsigned v = __hip_atomic_load(&g_flags[lane * 32],
                                                   __ATOMIC_RELAXED,
                                                   __HIP_MEMORY_SCOPE_AGENT);
                    if (__all((int)(v >= tgt))) break;
                    __builtin_amdgcn_s_sleep(1);
                }
            }
            asm volatile("" ::: "memory");
            __syncthreads();
        }
    }

    // Epilogue: final Y row (t = 511).
    #pragma unroll
    for (int j = 0; j < 4; ++j) {
        int row = 16 * w + (lane >> 4) * 4 + j;
        Y[(size_t)(T_T - 1) * (T_B * T_K) + (size_t)row * T_K + colL] = hreg[j];
    }
}

extern "C" void kernel_launch(void* const* d_in, const int* in_sizes, int n_in,
                              void* d_out, int out_size, void* d_ws, size_t ws_size,
                              hipStream_t stream)
{
    const float* X   = (const float*)d_in[0];
    const float* H0  = (const float*)d_in[1];
    const float* Wih = (const float*)d_in[2];
    const float* Whh = (const float*)d_in[3];
    const float* Bih = (const float*)d_in[4];
    const float* Bhh = (const float*)d_in[5];
    float* Y = (float*)d_out;
    (void)d_ws; (void)ws_size; (void)in_sizes; (void)n_in; (void)out_size;

    reset_flags_k<<<dim3(1), dim3(256), 0, stream>>>();

    cvt_k<<<dim3(2048), dim3(256), 0, stream>>>(X, Wih);

    gi_gemm<<<dim3(256 * 24), dim3(256), 0, stream>>>(Bih);

    gru_scan<<<dim3(64), dim3(256), 0, stream>>>(Whh, Bhh, H0, Y);
}

// Round 13
// 4056.190 us; speedup vs baseline: 1.0856x; 1.0856x over previous
//
#include <hip/hip_runtime.h>
#include <hip/hip_bf16.h>
#include <hip/hip_fp16.h>

// GRU forward, MI355X. Harness gives f32 buffers (reference f16 -> f32).
// x:(512,64,1024) h0:(1,64,1024) w_ih,w_hh:(3072,1024) b:(3072) y:(512,64,1024).
//
// PROTOCOL (r2/4/8/9/11/12, six-times-proven, absmax 0.0078125):
// per-step: gate math writes Y (cached) then h (packed u32 RELAXED agent
// write-through) inside the gate loop; s_waitcnt vmcnt(0); __syncthreads;
// tid0 stores flag (RELAXED agent, PRIVATE 128B line); gi prefetch; wave0
// gather-polls 64 flags w/ s_sleep; __syncthreads. r9 load-pin kept.
//
// FROZEN BY EXPERIMENT:
//  - Y AFTER the flag store    -> absmax 0.117 (r3, r6)
//  - nontemporal loads/stores  -> absmax 0.117 (r3)
//  - per-band per-STEP fetch_add sync -> absmax 0.048 + slow (r5)
//  - flags packed 4B stride    -> absmax 0.083 (r7)
//  - gi_gemm BK=64 reg-staged  -> +200us (r10)
//  - Y lag-by-one / 2-phase gemm -> null (r12)
//
// Round 20 (this round): FUSE producer and consumer. One launch:
//  - bid 0..63: r11 scan VERBATIM + gi-gating (two load-only insertions).
//  - bid 64..6207: r9 reg-staged GEMM tile (ascending m = ascending t),
//    g_gi stored via RELAXED agent write-through; per-thread vmcnt(0);
//    __syncthreads; tid0 atomicAdd on per-m-tile counter (private 128B
//    line, 24 one-shot adds) + global done counter. Exactly the proven
//    h-protocol handoff shape. cvt pass eliminated (reads f32 directly).
//  Scan gates gi reads on counter[t>>1]>=24 with an all_done latch
//  (done==6144) so steady-state gating cost ~0. gemm production outruns
//  scan consumption ~9x, so gi-side time hides under the scan.
//  Deadlock-free: gemm blocks never wait -> always drain -> all 64 scan
//  blocks eventually co-resident. Stale-L2 replay safe: gi deterministic.

typedef __attribute__((ext_vector_type(8))) _Float16 f16x8;
typedef __attribute__((ext_vector_type(4))) float f32x4;
typedef __attribute__((ext_vector_type(8))) float f32x8;

#define MFMA(a, b, c) __builtin_amdgcn_mfma_f32_16x16x32_f16((a), (b), (c), 0, 0, 0)

#define T_T 512
#define T_B 64
#define T_K 1024
#define T_N3 3072
#define N_SCAN 64
#define N_GEMM 6144

__device__ float          g_gi[(size_t)T_T * T_B * T_N3];   // 402 MiB f32 gi
__device__ unsigned short g_hbf[(size_t)T_T * T_B * T_K];   // 64 MiB f16 h_t
__device__ unsigned       g_flags[64 * 32];                 // 128B-padded h flags
__device__ unsigned       g_mtc[256 * 32];                  // 128B-padded m-tile counters
__device__ unsigned       g_gdone[32];                      // global gemm-done counter

static __device__ __forceinline__ f16x8 cvt8(f32x8 v) {
    f16x8 r;
    #pragma unroll
    for (int i = 0; i < 8; ++i) r[i] = (_Float16)v[i];
    return r;
}
static __device__ __forceinline__ float sigmoidf_(float x) {
    return 1.0f / (1.0f + __expf(-x));
}
static __device__ __forceinline__ float tanhf_(float x) {
    return 2.0f / (1.0f + __expf(-2.0f * x)) - 1.0f;
}

__global__ __launch_bounds__(256) void reset_flags_k() {
    for (int i = threadIdx.x; i < 64 * 32; i += 256) g_flags[i] = 0;
    for (int i = threadIdx.x; i < 256 * 32; i += 256) g_mtc[i] = 0;
    if (threadIdx.x < 32) g_gdone[threadIdx.x] = 0;
}

// ---------------------------------------------------------------------------
// Fused kernel: 64 persistent scan blocks + 6144 gemm tile blocks.
// ---------------------------------------------------------------------------
__global__ __launch_bounds__(256, 1) void fused_k(
    const float* __restrict__ X,     // (32768,1024) f32
    const float* __restrict__ Wih,   // (3072,1024) f32
    const float* __restrict__ Whh,   // (3072,1024) f32
    const float* __restrict__ Bih,   // (3072,) f32
    const float* __restrict__ Bhh,   // (3072,) f32
    const float* __restrict__ H0,    // (64,1024) f32
    float* Y)                        // (512,64,1024) f32
{
    __shared__ __align__(16) unsigned short smem[48 * 1024];  // 96 KiB
    const int tid = threadIdx.x;
    const int bid = blockIdx.x;

    if (bid >= N_SCAN) {
        // ================= GEMM role (r9 structure, proven) =================
        const int g    = bid - N_SCAN;          // 0..6143, ascending m
        const int lane = tid & 63;
        const int wid  = tid >> 6;
        const int m0 = (g / 24) * 128;
        const int n0 = (g % 24) * 128;
        const int wm = wid >> 1, wn = wid & 1;
        unsigned short* lA = smem;              // 8 KiB
        unsigned short* lB = smem + 4096;       // 8 KiB

        f32x4 acc[4][4] = {};

        for (int k0 = 0; k0 < T_K; k0 += 32) {
            #pragma unroll
            for (int i = 0; i < 2; ++i) {
                int idx = tid + i * 256;
                int kc  = idx & 3;
                int row = idx >> 2;
                f32x8 va = *(const f32x8*)(X + (size_t)(m0 + row) * T_K + k0 + kc * 8);
                f32x8 vb = *(const f32x8*)(Wih + (size_t)(n0 + row) * T_K + k0 + kc * 8);
                *(f16x8*)((char*)lA + kc * 2048 + row * 16) = cvt8(va);
                *(f16x8*)((char*)lB + kc * 2048 + row * 16) = cvt8(vb);
            }
            __syncthreads();

            f16x8 a[4], b[4];
            #pragma unroll
            for (int mt = 0; mt < 4; ++mt) {
                int row = 64 * wm + 16 * mt + (lane & 15);
                a[mt] = *(const f16x8*)((const char*)lA + (lane >> 4) * 2048 + row * 16);
            }
            #pragma unroll
            for (int nt = 0; nt < 4; ++nt) {
                int row = 64 * wn + 16 * nt + (lane & 15);
                b[nt] = *(const f16x8*)((const char*)lB + (lane >> 4) * 2048 + row * 16);
            }
            #pragma unroll
            for (int mt = 0; mt < 4; ++mt)
                #pragma unroll
                for (int nt = 0; nt < 4; ++nt)
                    acc[mt][nt] = MFMA(a[mt], b[nt], acc[mt][nt]);
            __syncthreads();
        }

        // gi stores: RELAXED agent write-through (h-protocol pattern).
        #pragma unroll
        for (int mt = 0; mt < 4; ++mt) {
            int rbase = m0 + 64 * wm + 16 * mt + (lane >> 4) * 4;
            #pragma unroll
            for (int nt = 0; nt < 4; ++nt) {
                int col = n0 + 64 * wn + 16 * nt + (lane & 15);
                float bv = Bih[col];
                #pragma unroll
                for (int j = 0; j < 4; ++j)
                    __hip_atomic_store(&g_gi[(size_t)(rbase + j) * T_N3 + col],
                                       acc[mt][nt][j] + bv,
                                       __ATOMIC_RELAXED, __HIP_MEMORY_SCOPE_AGENT);
            }
        }
        // Drain -> block barrier -> tid0 signals (proven handoff shape).
        asm volatile("s_waitcnt vmcnt(0)" ::: "memory");
        __syncthreads();
        if (tid == 0) {
            __hip_atomic_fetch_add(&g_mtc[(g / 24) * 32], 1u,
                                   __ATOMIC_RELAXED, __HIP_MEMORY_SCOPE_AGENT);
            __hip_atomic_fetch_add(&g_gdone[0], 1u,
                                   __ATOMIC_RELAXED, __HIP_MEMORY_SCOPE_AGENT);
        }
        return;
    }

    // ================= SCAN role (r11 verbatim + gi gates) =================
    unsigned short* Wl = smem;                  // 96 KiB f16
    const int lane = tid & 63;
    const int w    = tid >> 6;
    const int c0   = bid * 16;

    for (int idx = tid; idx < 48 * 128; idx += 256) {
        int row = idx >> 7;                   // gate*16 + c
        int kc  = idx & 127;
        int gate = row >> 4, cc = row & 15;
        f32x8 v = *(const f32x8*)(Whh + (size_t)(gate * 1024 + c0 + cc) * T_K + kc * 8);
        *(f16x8*)((char*)Wl + kc * 768 + row * 16) = cvt8(v);
    }
    const int colL = c0 + (lane & 15);
    const float br = Bhh[colL];
    const float bz = Bhh[1024 + colL];
    const float bn = Bhh[2048 + colL];
    __syncthreads();

    const char* bbase = (const char*)Wl + (lane >> 4) * 768 + (lane & 15) * 16;

    // gi-gating state (uniform registers).
    bool all_done = false;
    int  gmax = -1;

    // --- gate m-tile 0 before the t=0 gi preload ---
    {
        for (;;) {
            unsigned gd = __hip_atomic_load(&g_gdone[0], __ATOMIC_RELAXED,
                                            __HIP_MEMORY_SCOPE_AGENT);
            if (gd >= (unsigned)N_GEMM) { all_done = true; break; }
            unsigned v = __hip_atomic_load(&g_mtc[0], __ATOMIC_RELAXED,
                                           __HIP_MEMORY_SCOPE_AGENT);
            if (v >= 24u) break;
            __builtin_amdgcn_s_sleep(8);
        }
        gmax = 0;
    }

    // Preload gi for t = 0 (f32, normal cached loads).
    float pr[4], pz[4], pn[4];
    #pragma unroll
    for (int j = 0; j < 4; ++j) {
        int row = 16 * w + (lane >> 4) * 4 + j;
        pr[j] = g_gi[(size_t)row * T_N3 + colL];
        pz[j] = g_gi[(size_t)row * T_N3 + 1024 + colL];
        pn[j] = g_gi[(size_t)row * T_N3 + 2048 + colL];
    }

    // Per-thread h chain registers (f16-rounded values, kept as f32).
    float hreg[4];

    for (int t = 0; t < T_T; ++t) {
        f32x4 ar = {0.f, 0.f, 0.f, 0.f}, az = ar, an = ar;

        if (t == 0) {
            const float* abase =
                H0 + (size_t)(16 * w + (lane & 15)) * T_K + (lane >> 4) * 8;
            #pragma unroll 4
            for (int kk = 0; kk < 32; ++kk) {
                f16x8 af = cvt8(*(const f32x8*)(abase + kk * 32));
                const char* bb = bbase + kk * 3072;
                ar = MFMA(af, *(const f16x8*)(bb),       ar);
                az = MFMA(af, *(const f16x8*)(bb + 256), az);
                an = MFMA(af, *(const f16x8*)(bb + 512), an);
            }
        } else {
            const unsigned short* abase = g_hbf + (size_t)(t - 1) * (T_B * T_K)
                + (size_t)(16 * w + (lane & 15)) * T_K + (lane >> 4) * 8;
            // Issue ALL 32 independent b128 loads, then a may-write asm
            // barrier: loads cannot sink past it -> one latency exposure.
            f16x8 af[32];
            #pragma unroll
            for (int kk = 0; kk < 32; ++kk)
                af[kk] = *(const f16x8*)(abase + kk * 32);
            asm volatile("" ::: "memory");
            #pragma unroll
            for (int kk = 0; kk < 32; ++kk) {
                const char* bb = bbase + kk * 3072;
                ar = MFMA(af[kk], *(const f16x8*)(bb),       ar);
                az = MFMA(af[kk], *(const f16x8*)(bb + 256), az);
                an = MFMA(af[kk], *(const f16x8*)(bb + 512), an);
            }
        }

        #pragma unroll
        for (int j = 0; j < 4; ++j) {
            int row = 16 * w + (lane >> 4) * 4 + j;
            size_t off = (size_t)row * T_K + colL;
            float hp = (t == 0) ? H0[off] : hreg[j];
            float r = sigmoidf_(pr[j] + ar[j] + br);
            float z = sigmoidf_(pz[j] + az[j] + bz);
            float n = tanhf_(pn[j] + r * (an[j] + bn));
            float h = (1.0f - z) * n + z * hp;
            __half h16 = __float2half(h);         // reference: astype(f16)
            float  hq  = __half2float(h16);
            hreg[j] = hq;
            Y[(size_t)t * (T_B * T_K) + off] = hq;

            // f16 h -> g_hbf via packed u32 relaxed agent store (write-through).
            unsigned v16 = (unsigned)__half_as_ushort(h16);
            unsigned up  = __shfl_xor(v16, 1);
            if (!(lane & 1)) {
                unsigned packed = v16 | (up << 16);
                unsigned* dst = (unsigned*)(g_hbf + (size_t)t * (T_B * T_K) + off);
                __hip_atomic_store(dst, packed, __ATOMIC_RELAXED,
                                   __HIP_MEMORY_SCOPE_AGENT);
            }
        }

        if (t + 1 < T_T) {
            // Drain all vmem (h write-through included), then signal. No fence.
            asm volatile("s_waitcnt vmcnt(0)" ::: "memory");
            __syncthreads();
            if (tid == 0)
                __hip_atomic_store(&g_flags[bid * 32], (unsigned)(t + 1),
                                   __ATOMIC_RELAXED, __HIP_MEMORY_SCOPE_AGENT);

            // --- gate gi m-tile for t+1 (load-only; no stores moved) ---
            if (!all_done) {
                int needed = (t + 1) >> 1;
                if (needed > gmax) {
                    for (;;) {
                        unsigned gd = __hip_atomic_load(&g_gdone[0],
                                                        __ATOMIC_RELAXED,
                                                        __HIP_MEMORY_SCOPE_AGENT);
                        if (gd >= (unsigned)N_GEMM) { all_done = true; break; }
                        unsigned v = __hip_atomic_load(&g_mtc[needed * 32],
                                                       __ATOMIC_RELAXED,
                                                       __HIP_MEMORY_SCOPE_AGENT);
                        if (v >= 24u) break;
                        __builtin_amdgcn_s_sleep(8);
                    }
                    gmax = needed;
                }
            }

            // Prefetch gi for t+1 while polling (normal cached loads).
            const float* g = g_gi + (size_t)(t + 1) * T_B * T_N3;
            #pragma unroll
            for (int j = 0; j < 4; ++j) {
                int row = 16 * w + (lane >> 4) * 4 + j;
                pr[j] = g[(size_t)row * T_N3 + colL];
                pz[j] = g[(size_t)row * T_N3 + 1024 + colL];
                pn[j] = g[(size_t)row * T_N3 + 2048 + colL];
            }

            if (w == 0) {
                unsigned tgt = (unsigned)(t + 1);
                for (;;) {
                    unsigned v = __hip_atomic_load(&g_flags[lane * 32],
                                                   __ATOMIC_RELAXED,
                                                   __HIP_MEMORY_SCOPE_AGENT);
                    if (__all((int)(v >= tgt))) break;
                    __builtin_amdgcn_s_sleep(1);
                }
            }
            asm volatile("" ::: "memory");
            __syncthreads();
        }
    }
}

extern "C" void kernel_launch(void* const* d_in, const int* in_sizes, int n_in,
                              void* d_out, int out_size, void* d_ws, size_t ws_size,
                              hipStream_t stream)
{
    const float* X   = (const float*)d_in[0];
    const float* H0  = (const float*)d_in[1];
    const float* Wih = (const float*)d_in[2];
    const float* Whh = (const float*)d_in[3];
    const float* Bih = (const float*)d_in[4];
    const float* Bhh = (const float*)d_in[5];
    float* Y = (float*)d_out;
    (void)d_ws; (void)ws_size; (void)in_sizes; (void)n_in; (void)out_size;

    reset_flags_k<<<dim3(1), dim3(256), 0, stream>>>();

    fused_k<<<dim3(N_SCAN + N_GEMM), dim3(256), 0, stream>>>(
        X, Wih, Whh, Bih, Bhh, H0, Y);
}

// Round 14
// 4043.775 us; speedup vs baseline: 1.0889x; 1.0031x over previous
//
#include <hip/hip_runtime.h>
#include <hip/hip_bf16.h>
#include <hip/hip_fp16.h>

// GRU forward, MI355X. Harness gives f32 buffers (reference f16 -> f32).
// x:(512,64,1024) h0:(1,64,1024) w_ih,w_hh:(3072,1024) b:(3072) y:(512,64,1024).
//
// PROTOCOL (r2/4/8/9/11/12/13, seven-times-proven, absmax 0.0078125):
// per-step: gate math writes Y (cached) then h (packed u32 RELAXED agent
// write-through) inside the gate loop; s_waitcnt vmcnt(0); __syncthreads;
// tid0 stores flag (RELAXED agent, PRIVATE 128B line); gi prefetch; wave0
// gather-polls 64 flags w/ s_sleep; __syncthreads. r9 load-pin kept.
//
// FROZEN BY EXPERIMENT:
//  - Y AFTER the flag store    -> absmax 0.117 (r3, r6)
//  - nontemporal loads/stores  -> absmax 0.117 (r3)
//  - per-band per-STEP fetch_add sync -> absmax 0.048 + slow (r5)
//  - flags packed 4B stride    -> absmax 0.083 (r7)
//  - gi_gemm BK=64 reg-staged  -> +200us (r10)
//  - Y lag-by-one / 2-phase gemm -> null (r12)
//
// r13 (PASSED, 4056us): fused producer+consumer. 64 scan blocks (r11
// verbatim + load-only gi gates) + 6144 gemm blocks (r9 structure, gi via
// relaxed-agent write-through + proven handoff shape). cvt pass gone.
//
// Round 21 (this round): ONE change, protocol-distant -- gemm-role LDS
// bank-conflict fix. Old plane stride kc*2048: quarter-wave bank =
// (row*4)%32, the 4 kc-lanes per row collide -> 4-way ds_write_b128
// conflict (SQ_LDS_BANK_CONFLICT 7.58e7). New stride kc*2080 (+32B pad):
// bank = (kc*8 + row*4)%32, all 16 lanes distinct. Write & read use the
// same formula -> staged values/fragments/MFMA order bit-identical.

typedef __attribute__((ext_vector_type(8))) _Float16 f16x8;
typedef __attribute__((ext_vector_type(4))) float f32x4;
typedef __attribute__((ext_vector_type(8))) float f32x8;

#define MFMA(a, b, c) __builtin_amdgcn_mfma_f32_16x16x32_f16((a), (b), (c), 0, 0, 0)

#define T_T 512
#define T_B 64
#define T_K 1024
#define T_N3 3072
#define N_SCAN 64
#define N_GEMM 6144

__device__ float          g_gi[(size_t)T_T * T_B * T_N3];   // 402 MiB f32 gi
__device__ unsigned short g_hbf[(size_t)T_T * T_B * T_K];   // 64 MiB f16 h_t
__device__ unsigned       g_flags[64 * 32];                 // 128B-padded h flags
__device__ unsigned       g_mtc[256 * 32];                  // 128B-padded m-tile counters
__device__ unsigned       g_gdone[32];                      // global gemm-done counter

static __device__ __forceinline__ f16x8 cvt8(f32x8 v) {
    f16x8 r;
    #pragma unroll
    for (int i = 0; i < 8; ++i) r[i] = (_Float16)v[i];
    return r;
}
static __device__ __forceinline__ float sigmoidf_(float x) {
    return 1.0f / (1.0f + __expf(-x));
}
static __device__ __forceinline__ float tanhf_(float x) {
    return 2.0f / (1.0f + __expf(-2.0f * x)) - 1.0f;
}

__global__ __launch_bounds__(256) void reset_flags_k() {
    for (int i = threadIdx.x; i < 64 * 32; i += 256) g_flags[i] = 0;
    for (int i = threadIdx.x; i < 256 * 32; i += 256) g_mtc[i] = 0;
    if (threadIdx.x < 32) g_gdone[threadIdx.x] = 0;
}

// ---------------------------------------------------------------------------
// Fused kernel: 64 persistent scan blocks + 6144 gemm tile blocks.
// ---------------------------------------------------------------------------
__global__ __launch_bounds__(256, 1) void fused_k(
    const float* __restrict__ X,     // (32768,1024) f32
    const float* __restrict__ Wih,   // (3072,1024) f32
    const float* __restrict__ Whh,   // (3072,1024) f32
    const float* __restrict__ Bih,   // (3072,) f32
    const float* __restrict__ Bhh,   // (3072,) f32
    const float* __restrict__ H0,    // (64,1024) f32
    float* Y)                        // (512,64,1024) f32
{
    __shared__ __align__(16) unsigned short smem[48 * 1024];  // 96 KiB
    const int tid = threadIdx.x;
    const int bid = blockIdx.x;

    if (bid >= N_SCAN) {
        // ================= GEMM role (r9 structure + bank-pad) =============
        const int g    = bid - N_SCAN;          // 0..6143, ascending m
        const int lane = tid & 63;
        const int wid  = tid >> 6;
        const int m0 = (g / 24) * 128;
        const int n0 = (g % 24) * 128;
        const int wm = wid >> 1, wn = wid & 1;
        // Padded planes: 4 x 2080 B per matrix (16B-aligned).
        unsigned short* lA = smem;              // 8320 B
        unsigned short* lB = smem + 4160;       // 8320 B

        f32x4 acc[4][4] = {};

        for (int k0 = 0; k0 < T_K; k0 += 32) {
            #pragma unroll
            for (int i = 0; i < 2; ++i) {
                int idx = tid + i * 256;
                int kc  = idx & 3;
                int row = idx >> 2;
                f32x8 va = *(const f32x8*)(X + (size_t)(m0 + row) * T_K + k0 + kc * 8);
                f32x8 vb = *(const f32x8*)(Wih + (size_t)(n0 + row) * T_K + k0 + kc * 8);
                *(f16x8*)((char*)lA + kc * 2080 + row * 16) = cvt8(va);
                *(f16x8*)((char*)lB + kc * 2080 + row * 16) = cvt8(vb);
            }
            __syncthreads();

            f16x8 a[4], b[4];
            #pragma unroll
            for (int mt = 0; mt < 4; ++mt) {
                int row = 64 * wm + 16 * mt + (lane & 15);
                a[mt] = *(const f16x8*)((const char*)lA + (lane >> 4) * 2080 + row * 16);
            }
            #pragma unroll
            for (int nt = 0; nt < 4; ++nt) {
                int row = 64 * wn + 16 * nt + (lane & 15);
                b[nt] = *(const f16x8*)((const char*)lB + (lane >> 4) * 2080 + row * 16);
            }
            #pragma unroll
            for (int mt = 0; mt < 4; ++mt)
                #pragma unroll
                for (int nt = 0; nt < 4; ++nt)
                    acc[mt][nt] = MFMA(a[mt], b[nt], acc[mt][nt]);
            __syncthreads();
        }

        // gi stores: RELAXED agent write-through (h-protocol pattern).
        #pragma unroll
        for (int mt = 0; mt < 4; ++mt) {
            int rbase = m0 + 64 * wm + 16 * mt + (lane >> 4) * 4;
            #pragma unroll
            for (int nt = 0; nt < 4; ++nt) {
                int col = n0 + 64 * wn + 16 * nt + (lane & 15);
                float bv = Bih[col];
                #pragma unroll
                for (int j = 0; j < 4; ++j)
                    __hip_atomic_store(&g_gi[(size_t)(rbase + j) * T_N3 + col],
                                       acc[mt][nt][j] + bv,
                                       __ATOMIC_RELAXED, __HIP_MEMORY_SCOPE_AGENT);
            }
        }
        // Drain -> block barrier -> tid0 signals (proven handoff shape).
        asm volatile("s_waitcnt vmcnt(0)" ::: "memory");
        __syncthreads();
        if (tid == 0) {
            __hip_atomic_fetch_add(&g_mtc[(g / 24) * 32], 1u,
                                   __ATOMIC_RELAXED, __HIP_MEMORY_SCOPE_AGENT);
            __hip_atomic_fetch_add(&g_gdone[0], 1u,
                                   __ATOMIC_RELAXED, __HIP_MEMORY_SCOPE_AGENT);
        }
        return;
    }

    // ================= SCAN role (r11 verbatim + gi gates) =================
    unsigned short* Wl = smem;                  // 96 KiB f16
    const int lane = tid & 63;
    const int w    = tid >> 6;
    const int c0   = bid * 16;

    for (int idx = tid; idx < 48 * 128; idx += 256) {
        int row = idx >> 7;                   // gate*16 + c
        int kc  = idx & 127;
        int gate = row >> 4, cc = row & 15;
        f32x8 v = *(const f32x8*)(Whh + (size_t)(gate * 1024 + c0 + cc) * T_K + kc * 8);
        *(f16x8*)((char*)Wl + kc * 768 + row * 16) = cvt8(v);
    }
    const int colL = c0 + (lane & 15);
    const float br = Bhh[colL];
    const float bz = Bhh[1024 + colL];
    const float bn = Bhh[2048 + colL];
    __syncthreads();

    const char* bbase = (const char*)Wl + (lane >> 4) * 768 + (lane & 15) * 16;

    // gi-gating state (uniform registers).
    bool all_done = false;
    int  gmax = -1;

    // --- gate m-tile 0 before the t=0 gi preload ---
    {
        for (;;) {
            unsigned gd = __hip_atomic_load(&g_gdone[0], __ATOMIC_RELAXED,
                                            __HIP_MEMORY_SCOPE_AGENT);
            if (gd >= (unsigned)N_GEMM) { all_done = true; break; }
            unsigned v = __hip_atomic_load(&g_mtc[0], __ATOMIC_RELAXED,
                                           __HIP_MEMORY_SCOPE_AGENT);
            if (v >= 24u) break;
            __builtin_amdgcn_s_sleep(8);
        }
        gmax = 0;
    }

    // Preload gi for t = 0 (f32, normal cached loads).
    float pr[4], pz[4], pn[4];
    #pragma unroll
    for (int j = 0; j < 4; ++j) {
        int row = 16 * w + (lane >> 4) * 4 + j;
        pr[j] = g_gi[(size_t)row * T_N3 + colL];
        pz[j] = g_gi[(size_t)row * T_N3 + 1024 + colL];
        pn[j] = g_gi[(size_t)row * T_N3 + 2048 + colL];
    }

    // Per-thread h chain registers (f16-rounded values, kept as f32).
    float hreg[4];

    for (int t = 0; t < T_T; ++t) {
        f32x4 ar = {0.f, 0.f, 0.f, 0.f}, az = ar, an = ar;

        if (t == 0) {
            const float* abase =
                H0 + (size_t)(16 * w + (lane & 15)) * T_K + (lane >> 4) * 8;
            #pragma unroll 4
            for (int kk = 0; kk < 32; ++kk) {
                f16x8 af = cvt8(*(const f32x8*)(abase + kk * 32));
                const char* bb = bbase + kk * 3072;
                ar = MFMA(af, *(const f16x8*)(bb),       ar);
                az = MFMA(af, *(const f16x8*)(bb + 256), az);
                an = MFMA(af, *(const f16x8*)(bb + 512), an);
            }
        } else {
            const unsigned short* abase = g_hbf + (size_t)(t - 1) * (T_B * T_K)
                + (size_t)(16 * w + (lane & 15)) * T_K + (lane >> 4) * 8;
            // Issue ALL 32 independent b128 loads, then a may-write asm
            // barrier: loads cannot sink past it -> one latency exposure.
            f16x8 af[32];
            #pragma unroll
            for (int kk = 0; kk < 32; ++kk)
                af[kk] = *(const f16x8*)(abase + kk * 32);
            asm volatile("" ::: "memory");
            #pragma unroll
            for (int kk = 0; kk < 32; ++kk) {
                const char* bb = bbase + kk * 3072;
                ar = MFMA(af[kk], *(const f16x8*)(bb),       ar);
                az = MFMA(af[kk], *(const f16x8*)(bb + 256), az);
                an = MFMA(af[kk], *(const f16x8*)(bb + 512), an);
            }
        }

        #pragma unroll
        for (int j = 0; j < 4; ++j) {
            int row = 16 * w + (lane >> 4) * 4 + j;
            size_t off = (size_t)row * T_K + colL;
            float hp = (t == 0) ? H0[off] : hreg[j];
            float r = sigmoidf_(pr[j] + ar[j] + br);
            float z = sigmoidf_(pz[j] + az[j] + bz);
            float n = tanhf_(pn[j] + r * (an[j] + bn));
            float h = (1.0f - z) * n + z * hp;
            __half h16 = __float2half(h);         // reference: astype(f16)
            float  hq  = __half2float(h16);
            hreg[j] = hq;
            Y[(size_t)t * (T_B * T_K) + off] = hq;

            // f16 h -> g_hbf via packed u32 relaxed agent store (write-through).
            unsigned v16 = (unsigned)__half_as_ushort(h16);
            unsigned up  = __shfl_xor(v16, 1);
            if (!(lane & 1)) {
                unsigned packed = v16 | (up << 16);
                unsigned* dst = (unsigned*)(g_hbf + (size_t)t * (T_B * T_K) + off);
                __hip_atomic_store(dst, packed, __ATOMIC_RELAXED,
                                   __HIP_MEMORY_SCOPE_AGENT);
            }
        }

        if (t + 1 < T_T) {
            // Drain all vmem (h write-through included), then signal. No fence.
            asm volatile("s_waitcnt vmcnt(0)" ::: "memory");
            __syncthreads();
            if (tid == 0)
                __hip_atomic_store(&g_flags[bid * 32], (unsigned)(t + 1),
                                   __ATOMIC_RELAXED, __HIP_MEMORY_SCOPE_AGENT);

            // --- gate gi m-tile for t+1 (load-only; no stores moved) ---
            if (!all_done) {
                int needed = (t + 1) >> 1;
                if (needed > gmax) {
                    for (;;) {
                        unsigned gd = __hip_atomic_load(&g_gdone[0],
                                                        __ATOMIC_RELAXED,
                                                        __HIP_MEMORY_SCOPE_AGENT);
                        if (gd >= (unsigned)N_GEMM) { all_done = true; break; }
                        unsigned v = __hip_atomic_load(&g_mtc[needed * 32],
                                                       __ATOMIC_RELAXED,
                                                       __HIP_MEMORY_SCOPE_AGENT);
                        if (v >= 24u) break;
                        __builtin_amdgcn_s_sleep(8);
                    }
                    gmax = needed;
                }
            }

            // Prefetch gi for t+1 while polling (normal cached loads).
            const float* g = g_gi + (size_t)(t + 1) * T_B * T_N3;
            #pragma unroll
            for (int j = 0; j < 4; ++j) {
                int row = 16 * w + (lane >> 4) * 4 + j;
                pr[j] = g[(size_t)row * T_N3 + colL];
                pz[j] = g[(size_t)row * T_N3 + 1024 + colL];
                pn[j] = g[(size_t)row * T_N3 + 2048 + colL];
            }

            if (w == 0) {
                unsigned tgt = (unsigned)(t + 1);
                for (;;) {
                    unsigned v = __hip_atomic_load(&g_flags[lane * 32],
                                                   __ATOMIC_RELAXED,
                                                   __HIP_MEMORY_SCOPE_AGENT);
                    if (__all((int)(v >= tgt))) break;
                    __builtin_amdgcn_s_sleep(1);
                }
            }
            asm volatile("" ::: "memory");
            __syncthreads();
        }
    }
}

extern "C" void kernel_launch(void* const* d_in, const int* in_sizes, int n_in,
                              void* d_out, int out_size, void* d_ws, size_t ws_size,
                              hipStream_t stream)
{
    const float* X   = (const float*)d_in[0];
    const float* H0  = (const float*)d_in[1];
    const float* Wih = (const float*)d_in[2];
    const float* Whh = (const float*)d_in[3];
    const float* Bih = (const float*)d_in[4];
    const float* Bhh = (const float*)d_in[5];
    float* Y = (float*)d_out;
    (void)d_ws; (void)ws_size; (void)in_sizes; (void)n_in; (void)out_size;

    reset_flags_k<<<dim3(1), dim3(256), 0, stream>>>();

    fused_k<<<dim3(N_SCAN + N_GEMM), dim3(256), 0, stream>>>(
        X, Wih, Whh, Bih, Bhh, H0, Y);
}